// Round 4
// baseline (300.692 us; speedup 1.0000x reference)
//
#include <hip/hip_runtime.h>

#define NB 1024

typedef __bf16 bf16x8 __attribute__((ext_vector_type(8)));
typedef float f32x4 __attribute__((ext_vector_type(4)));

union ABu { uint4 u; bf16x8 v; __bf16 b[8]; };
union P4  { uint2 u; __bf16 b[4]; };

__device__ __forceinline__ unsigned short f2bf(float f) {
    unsigned int u = __builtin_bit_cast(unsigned int, f);
    u += 0x7fffu + ((u >> 16) & 1u);   // RTNE
    return (unsigned short)(u >> 16);
}

// ---- prep 1: A[p][n] = x[p] @ W0[:64,:],  C[q][n] = y[q] @ W0[64:,:] + b0  (fp32) ----
__global__ void prep_ac(const float* __restrict__ x, const float* __restrict__ y,
                        const float* __restrict__ W0, const float* __restrict__ b0,
                        float* __restrict__ Aws, float* __restrict__ Cws) {
    __shared__ float row[64];
    int b = blockIdx.x;            // 0..1023 -> A rows, 1024..2047 -> C rows
    int t = threadIdx.x;           // 0..127  : output feature n
    bool isC = b >= 1024;
    int r = isC ? b - 1024 : b;
    const float* src = isC ? y : x;
    if (t < 64) row[t] = src[r * 64 + t];
    __syncthreads();
    const float* w = W0 + (isC ? 64 * 128 : 0);
    float acc = isC ? b0[t] : 0.f;
#pragma unroll
    for (int k = 0; k < 64; k++) acc += row[k] * w[k * 128 + t];
    (isC ? Cws : Aws)[r * 128 + t] = acc;
}

// ---- prep 2: transpose W1..W4 to bf16 [N][K] ----
__global__ void prep_w(const float* __restrict__ W1, const float* __restrict__ W2,
                       const float* __restrict__ W3, const float* __restrict__ W4,
                       unsigned short* __restrict__ W1t, unsigned short* __restrict__ W2t,
                       unsigned short* __restrict__ W3t, unsigned short* __restrict__ W4t) {
    int i = blockIdx.x * 256 + threadIdx.x;    // 32768 total
    if (i < 16384)      { int n = i >> 7, k = i & 127;               W1t[i] = f2bf(W1[k * 128 + n]); }
    else if (i < 24576) { int j = i - 16384; int n = j >> 7, k = j & 127; W2t[j] = f2bf(W2[k * 64 + n]); }
    else if (i < 28672) { int j = i - 24576; int n = j >> 6, k = j & 63;  W3t[j] = f2bf(W3[k * 64 + n]); }
    else                { int j = i - 28672; int n = j >> 6, k = j & 63;  W4t[j] = f2bf(W4[k * 64 + n]); }
}

#define MFMA(a, b, d) (d) = __builtin_amdgcn_mfma_f32_16x16x32_bf16((a), (b), (d), 0, 0, 0)

// ---- main: swapped-operand MFMA chain. A = W^T (features), B = h^T (pairs on lanes).
// Per wave: 32 pairs = 2 p-rows x 16 q-cols. One 4KB LDS tile [32 pairs][64 feats],
// reused by every layer transition. No barriers, wave-private.
__launch_bounds__(256, 3)
__global__ void critic_main(const float* __restrict__ Aws, const float* __restrict__ Cws,
                            const unsigned short* __restrict__ W1t, const unsigned short* __restrict__ W2t,
                            const unsigned short* __restrict__ W3t, const unsigned short* __restrict__ W4t,
                            const float* __restrict__ b1, const float* __restrict__ b2,
                            const float* __restrict__ b3, const float* __restrict__ b4,
                            const float* __restrict__ W5, const float* __restrict__ b5,
                            float* __restrict__ out) {
    __shared__ unsigned short hb[4][2048];     // 4KB per wave
    int tid = threadIdx.x;
    int w = tid >> 6, lane = tid & 63;
    int g = lane >> 4, c = lane & 15;
    int pw = (blockIdx.x >> 6) * 8 + w * 2;    // this wave's 2 p rows
    int qb = (blockIdx.x & 63) * 16;           // block's 16 q cols
    char* h = (char*)hb[w];
    const int swz = (c & 7) << 4;

    // ---- h0 B-frags: relu(A[p] + C[q]), kept in registers (8 frags, 32 VGPR) ----
    ABu af[4][2];   // [ks][pt]
#pragma unroll
    for (int ks = 0; ks < 4; ks++) {
        const float* cp = &Cws[(qb + c) * 128 + ks * 32 + 8 * g];
        f32x4 c0 = *(const f32x4*)cp;
        f32x4 c1 = *(const f32x4*)(cp + 4);
#pragma unroll
        for (int pt = 0; pt < 2; pt++) {
            const float* ap = &Aws[(pw + pt) * 128 + ks * 32 + 8 * g];
            f32x4 a0 = *(const f32x4*)ap;
            f32x4 a1 = *(const f32x4*)(ap + 4);
            ABu av;
#pragma unroll
            for (int j = 0; j < 4; j++) av.b[j]     = (__bf16)fmaxf(a0[j] + c0[j], 0.f);
#pragma unroll
            for (int j = 0; j < 4; j++) av.b[4 + j] = (__bf16)fmaxf(a1[j] + c1[j], 0.f);
            af[ks][pt] = av;
        }
    }

    f32x4 acc2[4][2];
#pragma unroll
    for (int i = 0; i < 4; i++)
#pragma unroll
        for (int j = 0; j < 2; j++) acc2[i][j] = (f32x4){0.f, 0.f, 0.f, 0.f};

    // ---- W1 (128->128) interleaved with W2 (128->64) in 64-feature halves ----
#pragma unroll
    for (int half = 0; half < 2; half++) {
        f32x4 accW[4][2];
#pragma unroll
        for (int i = 0; i < 4; i++)
#pragma unroll
            for (int j = 0; j < 2; j++) accW[i][j] = (f32x4){0.f, 0.f, 0.f, 0.f};
#pragma unroll
        for (int ks = 0; ks < 4; ks++) {
            ABu wf[4];
#pragma unroll
            for (int ft = 0; ft < 4; ft++)
                wf[ft].u = *(const uint4*)&W1t[(half * 64 + ft * 16 + c) * 128 + ks * 32 + 8 * g];
#pragma unroll
            for (int ft = 0; ft < 4; ft++)
#pragma unroll
                for (int pt = 0; pt < 2; pt++)
                    MFMA(wf[ft].v, af[ks][pt].v, accW[ft][pt]);
        }
        // epilogue: relu(acc + b1) -> bf16 -> h[pair][feat] (k-consecutive, b64 stores)
#pragma unroll
        for (int ft = 0; ft < 4; ft++) {
            f32x4 bias = *(const f32x4*)&b1[half * 64 + ft * 16 + 4 * g];
#pragma unroll
            for (int pt = 0; pt < 2; pt++) {
                P4 p;
#pragma unroll
                for (int r = 0; r < 4; r++) p.b[r] = (__bf16)fmaxf(accW[ft][pt][r] + bias[r], 0.f);
                *(uint2*)(h + (pt * 16 + c) * 128 + ((32 * ft + 8 * g) ^ swz)) = p.u;
            }
        }
        // W2 partial accumulation over this half's 64 k's
#pragma unroll
        for (int kss = 0; kss < 2; kss++) {
            int ks = half * 2 + kss;
            ABu wf[4];
#pragma unroll
            for (int ft = 0; ft < 4; ft++)
                wf[ft].u = *(const uint4*)&W2t[(ft * 16 + c) * 128 + ks * 32 + 8 * g];
            ABu bh[2];
#pragma unroll
            for (int pt = 0; pt < 2; pt++)
                bh[pt].u = *(const uint4*)(h + (pt * 16 + c) * 128 + ((kss * 64 + 16 * g) ^ swz));
#pragma unroll
            for (int ft = 0; ft < 4; ft++)
#pragma unroll
                for (int pt = 0; pt < 2; pt++)
                    MFMA(wf[ft].v, bh[pt].v, acc2[ft][pt]);
        }
    }

    // ---- W2 epilogue -> h ----
#pragma unroll
    for (int ft = 0; ft < 4; ft++) {
        f32x4 bias = *(const f32x4*)&b2[ft * 16 + 4 * g];
#pragma unroll
        for (int pt = 0; pt < 2; pt++) {
            P4 p;
#pragma unroll
            for (int r = 0; r < 4; r++) p.b[r] = (__bf16)fmaxf(acc2[ft][pt][r] + bias[r], 0.f);
            *(uint2*)(h + (pt * 16 + c) * 128 + ((32 * ft + 8 * g) ^ swz)) = p.u;
        }
    }

    // ---- W3 (64->64) ----
    f32x4 acc3[4][2];
#pragma unroll
    for (int i = 0; i < 4; i++)
#pragma unroll
        for (int j = 0; j < 2; j++) acc3[i][j] = (f32x4){0.f, 0.f, 0.f, 0.f};
#pragma unroll
    for (int ks = 0; ks < 2; ks++) {
        ABu wf[4];
#pragma unroll
        for (int ft = 0; ft < 4; ft++)
            wf[ft].u = *(const uint4*)&W3t[(ft * 16 + c) * 64 + ks * 32 + 8 * g];
        ABu bh[2];
#pragma unroll
        for (int pt = 0; pt < 2; pt++)
            bh[pt].u = *(const uint4*)(h + (pt * 16 + c) * 128 + ((ks * 64 + 16 * g) ^ swz));
#pragma unroll
        for (int ft = 0; ft < 4; ft++)
#pragma unroll
            for (int pt = 0; pt < 2; pt++)
                MFMA(wf[ft].v, bh[pt].v, acc3[ft][pt]);
    }
#pragma unroll
    for (int ft = 0; ft < 4; ft++) {
        f32x4 bias = *(const f32x4*)&b3[ft * 16 + 4 * g];
#pragma unroll
        for (int pt = 0; pt < 2; pt++) {
            P4 p;
#pragma unroll
            for (int r = 0; r < 4; r++) p.b[r] = (__bf16)fmaxf(acc3[ft][pt][r] + bias[r], 0.f);
            *(uint2*)(h + (pt * 16 + c) * 128 + ((32 * ft + 8 * g) ^ swz)) = p.u;
        }
    }

    // ---- W4 (64->64) ----
    f32x4 acc4[4][2];
#pragma unroll
    for (int i = 0; i < 4; i++)
#pragma unroll
        for (int j = 0; j < 2; j++) acc4[i][j] = (f32x4){0.f, 0.f, 0.f, 0.f};
#pragma unroll
    for (int ks = 0; ks < 2; ks++) {
        ABu wf[4];
#pragma unroll
        for (int ft = 0; ft < 4; ft++)
            wf[ft].u = *(const uint4*)&W4t[(ft * 16 + c) * 64 + ks * 32 + 8 * g];
        ABu bh[2];
#pragma unroll
        for (int pt = 0; pt < 2; pt++)
            bh[pt].u = *(const uint4*)(h + (pt * 16 + c) * 128 + ((ks * 64 + 16 * g) ^ swz));
#pragma unroll
        for (int ft = 0; ft < 4; ft++)
#pragma unroll
            for (int pt = 0; pt < 2; pt++)
                MFMA(wf[ft].v, bh[pt].v, acc4[ft][pt]);
    }

    // ---- final: out[pair] = relu(h4 + b4) . W5 + b5 (fp32, cross-g reduce) ----
    float b5s = b5[0];
#pragma unroll
    for (int pt = 0; pt < 2; pt++) {
        float s = 0.f;
#pragma unroll
        for (int ft = 0; ft < 4; ft++) {
            f32x4 bb = *(const f32x4*)&b4[ft * 16 + 4 * g];
            f32x4 ww = *(const f32x4*)&W5[ft * 16 + 4 * g];
#pragma unroll
            for (int r = 0; r < 4; r++)
                s += fmaxf(acc4[ft][pt][r] + bb[r], 0.f) * ww[r];
        }
        s += __shfl_xor(s, 16);
        s += __shfl_xor(s, 32);
        if (lane < 16)
            out[(pw + pt) * NB + qb + c] = s + b5s;
    }
}

extern "C" void kernel_launch(void* const* d_in, const int* in_sizes, int n_in,
                              void* d_out, int out_size, void* d_ws, size_t ws_size,
                              hipStream_t stream) {
    const float* x  = (const float*)d_in[0];
    const float* y  = (const float*)d_in[1];
    const float* W0 = (const float*)d_in[2];
    const float* b0 = (const float*)d_in[3];
    const float* W1 = (const float*)d_in[4];
    const float* b1 = (const float*)d_in[5];
    const float* W2 = (const float*)d_in[6];
    const float* b2 = (const float*)d_in[7];
    const float* W3 = (const float*)d_in[8];
    const float* b3 = (const float*)d_in[9];
    const float* W4 = (const float*)d_in[10];
    const float* b4 = (const float*)d_in[11];
    const float* W5 = (const float*)d_in[12];
    const float* b5 = (const float*)d_in[13];
    float* out = (float*)d_out;

    char* ws = (char*)d_ws;
    float* Aws = (float*)ws;                                    // 1024*128 f32 = 512KB
    float* Cws = (float*)(ws + 524288);                         // 512KB
    unsigned short* W1t = (unsigned short*)(ws + 1048576);      // 32KB (128x128)
    unsigned short* W2t = (unsigned short*)(ws + 1048576 + 32768);   // 16KB (64x128)
    unsigned short* W3t = (unsigned short*)(ws + 1048576 + 49152);   // 8KB  (64x64)
    unsigned short* W4t = (unsigned short*)(ws + 1048576 + 57344);   // 8KB  (64x64)

    prep_ac<<<2048, 128, 0, stream>>>(x, y, W0, b0, Aws, Cws);
    prep_w<<<128, 256, 0, stream>>>(W1, W2, W3, W4, W1t, W2t, W3t, W4t);
    critic_main<<<8192, 256, 0, stream>>>(Aws, Cws, W1t, W2t, W3t, W4t,
                                          b1, b2, b3, b4, W5, b5, out);
}

// Round 5
// 102.919 us; speedup vs baseline: 2.9216x; 2.9216x over previous
//
#include <hip/hip_runtime.h>

#define NB 1024

typedef __bf16 bf16x8 __attribute__((ext_vector_type(8)));
typedef float f32x4 __attribute__((ext_vector_type(4)));

union ABu { uint4 u; bf16x8 v; __bf16 b[8]; };

__device__ __forceinline__ unsigned short f2bf(float f) {
    unsigned int u = __builtin_bit_cast(unsigned int, f);
    u += 0x7fffu + ((u >> 16) & 1u);   // RTNE
    return (unsigned short)(u >> 16);
}

// ---- prep 1: A[p][n] = x[p] @ W0[:64,:],  C[q][n] = y[q] @ W0[64:,:] + b0  (fp32) ----
__global__ void prep_ac(const float* __restrict__ x, const float* __restrict__ y,
                        const float* __restrict__ W0, const float* __restrict__ b0,
                        float* __restrict__ Aws, float* __restrict__ Cws) {
    __shared__ float row[64];
    int b = blockIdx.x;
    int t = threadIdx.x;
    bool isC = b >= 1024;
    int r = isC ? b - 1024 : b;
    const float* src = isC ? y : x;
    if (t < 64) row[t] = src[r * 64 + t];
    __syncthreads();
    const float* w = W0 + (isC ? 64 * 128 : 0);
    float acc = isC ? b0[t] : 0.f;
#pragma unroll
    for (int k = 0; k < 64; k++) acc += row[k] * w[k * 128 + t];
    (isC ? Cws : Aws)[r * 128 + t] = acc;
}

// ---- prep 2: build fragment-major weight image (u16[32768] = 64KB) ----
// chunk layout: idx = ((ft*NKS + ks)*64 + g*16 + c)*8 + j  -> 16B chunk per (ft,ks,lane)
// W1 natural k; W2/W3/W4 k-permuted by sigma: f=16a+4gs+r -> slot 32(a&1)+8gs+4(a>>1)+r (+64H for W2)
__global__ void prep_img(const float* __restrict__ W1, const float* __restrict__ W2,
                         const float* __restrict__ W3, const float* __restrict__ W4,
                         unsigned short* __restrict__ img) {
    int i = blockIdx.x * 256 + threadIdx.x;    // 0..32767
    float val;
    if (i < 16384) {           // W1: ft 0..7, ks 0..3
        int j = i & 7, cc = (i >> 3) & 15, gg = (i >> 7) & 3, ks = (i >> 9) & 3, ft = i >> 11;
        int k = 32 * ks + 8 * gg + j, n = 16 * ft + cc;
        val = W1[k * 128 + n];
    } else if (i < 24576) {    // W2: ft 0..3, ks 0..3 (K=128, sigma with H)
        int d = i - 16384;
        int j = d & 7, cc = (d >> 3) & 15, gg = (d >> 7) & 3, ks = (d >> 9) & 3, ft = d >> 11;
        int s = 32 * ks + 8 * gg + j;
        int H = s >> 6, sp = s & 63;
        int a = ((sp >> 5) & 1) | (((sp >> 2) & 1) << 1);
        int gs = (sp >> 3) & 3, rr = sp & 3;
        int fin = 64 * H + 16 * a + 4 * gs + rr, n = 16 * ft + cc;
        val = W2[fin * 64 + n];
    } else {                   // W3 / W4: ft 0..3, ks 0..1 (K=64, sigma)
        int d = (i < 28672) ? i - 24576 : i - 28672;
        const float* W = (i < 28672) ? W3 : W4;
        int j = d & 7, cc = (d >> 3) & 15, gg = (d >> 7) & 3, ks = (d >> 9) & 1, ft = d >> 10;
        int s = 32 * ks + 8 * gg + j;
        int a = ((s >> 5) & 1) | (((s >> 2) & 1) << 1);
        int gs = (s >> 3) & 3, rr = s & 3;
        int fin = 16 * a + 4 * gs + rr, n = 16 * ft + cc;
        val = W[fin * 64 + n];
    }
    img[i] = f2bf(val);
}

#define MFMA(a, b, d) (d) = __builtin_amdgcn_mfma_f32_16x16x32_bf16((a), (b), (d), 0, 0, 0)

// byte offsets into the LDS weight image
#define W1OFF 0        // 8 ft * 4 ks * 1024B
#define W2OFF 32768    // 4 ft * 4 ks * 1024B
#define W3OFF 49152    // 4 ft * 2 ks * 1024B
#define W4OFF 57344

__launch_bounds__(512, 4)
__global__ void critic_main(const float* __restrict__ Aws, const float* __restrict__ Cws,
                            const unsigned short* __restrict__ Wimg,
                            const float* __restrict__ b1, const float* __restrict__ b2,
                            const float* __restrict__ b3, const float* __restrict__ b4,
                            const float* __restrict__ W5, const float* __restrict__ b5,
                            float* __restrict__ out) {
    __shared__ unsigned short Wl[32768];   // 64KB staged weights, shared by 8 waves
    int tid = threadIdx.x;

    // stage weights: linear 64KB copy, coalesced, conflict-free
    {
        const uint4* src = (const uint4*)Wimg;
        uint4* dst = (uint4*)Wl;
#pragma unroll
        for (int r = 0; r < 8; r++) dst[r * 512 + tid] = src[r * 512 + tid];
    }
    __syncthreads();

    int w = tid >> 6, lane = tid & 63;
    int g = lane >> 4, c = lane & 15;
    int pw = (blockIdx.x >> 6) * 16 + w * 2;   // wave's 2 p rows
    int qb = (blockIdx.x & 63) * 16;           // block's 16 q cols
    const char* WB = (const char*)Wl;
    int lo = lane * 16;                         // the ONE dynamic LDS offset

    // ---- h0 B-frags: relu(A[p] + C[q]), natural k ----
    ABu af[4][2];
#pragma unroll
    for (int ks = 0; ks < 4; ks++) {
        const float* cp = &Cws[(qb + c) * 128 + ks * 32 + 8 * g];
        f32x4 c0 = *(const f32x4*)cp, c1 = *(const f32x4*)(cp + 4);
#pragma unroll
        for (int pt = 0; pt < 2; pt++) {
            const float* ap = &Aws[(pw + pt) * 128 + ks * 32 + 8 * g];
            f32x4 a0 = *(const f32x4*)ap, a1 = *(const f32x4*)(ap + 4);
            ABu av;
#pragma unroll
            for (int j = 0; j < 4; j++) {
                av.b[j]     = (__bf16)fmaxf(a0[j] + c0[j], 0.f);
                av.b[4 + j] = (__bf16)fmaxf(a1[j] + c1[j], 0.f);
            }
            af[ks][pt] = av;
        }
    }

    f32x4 acc[4][2];
    ABu bh1[4][2];

    // ---- W1 (128->128), two 64-feat halves; outputs packed to sigma-slot B-frags ----
#pragma unroll
    for (int H = 0; H < 2; H++) {
#pragma unroll
        for (int a = 0; a < 4; a++)
#pragma unroll
            for (int pt = 0; pt < 2; pt++) acc[a][pt] = (f32x4){0.f, 0.f, 0.f, 0.f};
#pragma unroll
        for (int ks = 0; ks < 4; ks++) {
            ABu wf[4];
#pragma unroll
            for (int ftl = 0; ftl < 4; ftl++)
                wf[ftl].u = *(const uint4*)(WB + W1OFF + (H * 4 + ftl) * 4096 + ks * 1024 + lo);
#pragma unroll
            for (int ftl = 0; ftl < 4; ftl++)
#pragma unroll
                for (int pt = 0; pt < 2; pt++)
                    MFMA(wf[ftl].v, af[ks][pt].v, acc[ftl][pt]);
        }
#pragma unroll
        for (int pt = 0; pt < 2; pt++) {
            f32x4 t[4];
#pragma unroll
            for (int a = 0; a < 4; a++) {
                f32x4 bb = *(const f32x4*)&b1[H * 64 + a * 16 + 4 * g];
#pragma unroll
                for (int r = 0; r < 4; r++) t[a][r] = fmaxf(acc[a][pt][r] + bb[r], 0.f);
            }
#pragma unroll
            for (int ksp = 0; ksp < 2; ksp++) {
                ABu bv;
#pragma unroll
                for (int r = 0; r < 4; r++) {
                    bv.b[r]     = (__bf16)t[ksp][r];
                    bv.b[4 + r] = (__bf16)t[ksp + 2][r];
                }
                bh1[H * 2 + ksp][pt] = bv;
            }
        }
    }

    // ---- W2 (128->64) ----
    f32x4 acc2[4][2];
#pragma unroll
    for (int a = 0; a < 4; a++)
#pragma unroll
        for (int pt = 0; pt < 2; pt++) acc2[a][pt] = (f32x4){0.f, 0.f, 0.f, 0.f};
#pragma unroll
    for (int ks = 0; ks < 4; ks++) {
        ABu wf[4];
#pragma unroll
        for (int ft = 0; ft < 4; ft++)
            wf[ft].u = *(const uint4*)(WB + W2OFF + ft * 4096 + ks * 1024 + lo);
#pragma unroll
        for (int ft = 0; ft < 4; ft++)
#pragma unroll
            for (int pt = 0; pt < 2; pt++)
                MFMA(wf[ft].v, bh1[ks][pt].v, acc2[ft][pt]);
    }
    ABu bh2[2][2];
#pragma unroll
    for (int pt = 0; pt < 2; pt++) {
        f32x4 t[4];
#pragma unroll
        for (int a = 0; a < 4; a++) {
            f32x4 bb = *(const f32x4*)&b2[a * 16 + 4 * g];
#pragma unroll
            for (int r = 0; r < 4; r++) t[a][r] = fmaxf(acc2[a][pt][r] + bb[r], 0.f);
        }
#pragma unroll
        for (int ksp = 0; ksp < 2; ksp++) {
            ABu bv;
#pragma unroll
            for (int r = 0; r < 4; r++) {
                bv.b[r]     = (__bf16)t[ksp][r];
                bv.b[4 + r] = (__bf16)t[ksp + 2][r];
            }
            bh2[ksp][pt] = bv;
        }
    }

    // ---- W3 (64->64) ----
#pragma unroll
    for (int a = 0; a < 4; a++)
#pragma unroll
        for (int pt = 0; pt < 2; pt++) acc[a][pt] = (f32x4){0.f, 0.f, 0.f, 0.f};
#pragma unroll
    for (int ks = 0; ks < 2; ks++) {
        ABu wf[4];
#pragma unroll
        for (int ft = 0; ft < 4; ft++)
            wf[ft].u = *(const uint4*)(WB + W3OFF + ft * 2048 + ks * 1024 + lo);
#pragma unroll
        for (int ft = 0; ft < 4; ft++)
#pragma unroll
            for (int pt = 0; pt < 2; pt++)
                MFMA(wf[ft].v, bh2[ks][pt].v, acc[ft][pt]);
    }
    ABu bh3[2][2];
#pragma unroll
    for (int pt = 0; pt < 2; pt++) {
        f32x4 t[4];
#pragma unroll
        for (int a = 0; a < 4; a++) {
            f32x4 bb = *(const f32x4*)&b3[a * 16 + 4 * g];
#pragma unroll
            for (int r = 0; r < 4; r++) t[a][r] = fmaxf(acc[a][pt][r] + bb[r], 0.f);
        }
#pragma unroll
        for (int ksp = 0; ksp < 2; ksp++) {
            ABu bv;
#pragma unroll
            for (int r = 0; r < 4; r++) {
                bv.b[r]     = (__bf16)t[ksp][r];
                bv.b[4 + r] = (__bf16)t[ksp + 2][r];
            }
            bh3[ksp][pt] = bv;
        }
    }

    // ---- W4 (64->64) ----
#pragma unroll
    for (int a = 0; a < 4; a++)
#pragma unroll
        for (int pt = 0; pt < 2; pt++) acc[a][pt] = (f32x4){0.f, 0.f, 0.f, 0.f};
#pragma unroll
    for (int ks = 0; ks < 2; ks++) {
        ABu wf[4];
#pragma unroll
        for (int ft = 0; ft < 4; ft++)
            wf[ft].u = *(const uint4*)(WB + W4OFF + ft * 2048 + ks * 1024 + lo);
#pragma unroll
        for (int ft = 0; ft < 4; ft++)
#pragma unroll
            for (int pt = 0; pt < 2; pt++)
                MFMA(wf[ft].v, bh3[ks][pt].v, acc[ft][pt]);
    }

    // ---- final: out = relu(h4 + b4) . W5 + b5 (fp32, reduce over g-lanes) ----
    float b5s = b5[0];
#pragma unroll
    for (int pt = 0; pt < 2; pt++) {
        float s = 0.f;
#pragma unroll
        for (int a = 0; a < 4; a++) {
            f32x4 bb = *(const f32x4*)&b4[a * 16 + 4 * g];
            f32x4 ww = *(const f32x4*)&W5[a * 16 + 4 * g];
#pragma unroll
            for (int r = 0; r < 4; r++)
                s += fmaxf(acc[a][pt][r] + bb[r], 0.f) * ww[r];
        }
        s += __shfl_xor(s, 16);
        s += __shfl_xor(s, 32);
        if (lane < 16)
            out[(pw + pt) * NB + qb + c] = s + b5s;
    }
}

extern "C" void kernel_launch(void* const* d_in, const int* in_sizes, int n_in,
                              void* d_out, int out_size, void* d_ws, size_t ws_size,
                              hipStream_t stream) {
    const float* x  = (const float*)d_in[0];
    const float* y  = (const float*)d_in[1];
    const float* W0 = (const float*)d_in[2];
    const float* b0 = (const float*)d_in[3];
    const float* W1 = (const float*)d_in[4];
    const float* b1 = (const float*)d_in[5];
    const float* W2 = (const float*)d_in[6];
    const float* b2 = (const float*)d_in[7];
    const float* W3 = (const float*)d_in[8];
    const float* b3 = (const float*)d_in[9];
    const float* W4 = (const float*)d_in[10];
    const float* b4 = (const float*)d_in[11];
    const float* W5 = (const float*)d_in[12];
    const float* b5 = (const float*)d_in[13];
    float* out = (float*)d_out;

    char* ws = (char*)d_ws;
    float* Aws = (float*)ws;                                    // 1024*128 f32 = 512KB
    float* Cws = (float*)(ws + 524288);                         // 512KB
    unsigned short* Wimg = (unsigned short*)(ws + 1048576);     // 64KB fragment-major image

    prep_ac<<<2048, 128, 0, stream>>>(x, y, W0, b0, Aws, Cws);
    prep_img<<<128, 256, 0, stream>>>(W1, W2, W3, W4, Wimg);
    critic_main<<<4096, 512, 0, stream>>>(Aws, Cws, Wimg,
                                          b1, b2, b3, b4, W5, b5, out);
}